// Round 1
// baseline (3571.438 us; speedup 1.0000x reference)
//
#include <hip/hip_runtime.h>
#include <hip/hip_bf16.h>

#define BB 512
#define TT 1024
#define HH 100
#define VV 62
#define BTV (512*1024*62)

// ws float offsets
#define OFF_EP  52428800   // 62*100 table (padded region 6400)
#define OFF_WIT 52435200   // W_ih transposed for layers 1,2: [2][100][100] (wit[l][h][k])
#define OFF_WDT 52455200   // W_dec transposed+padded: [100][64]
#define OFF_BS  52461600   // bias sums layers 1,2: [2][100]
#define OFF_BDP 52461800   // b_dec padded to 64

__device__ inline float tanh_fast(float x){
  float ax = fabsf(x);
  float e  = __expf(2.0f*ax);
  float r  = 1.0f - __fdividef(2.0f, e + 1.0f);
  return copysignf(r, x);
}

__global__ void prep_kernel(
    const float* __restrict__ emb, const float* __restrict__ W_ih,
    const float* __restrict__ b_ih, const float* __restrict__ b_hh,
    const float* __restrict__ W_dec, const float* __restrict__ b_dec,
    float* __restrict__ ws)
{
  int g = blockIdx.x*256 + threadIdx.x;
  if (g < 6200){
    int v = g/100, k = g%100;
    float a = b_ih[k] + b_hh[k];
    const float* er = emb + v*100;
    const float* wr = W_ih + k*100;
    for (int h=0; h<100; h++) a = fmaf(er[h], wr[h], a);
    ws[OFF_EP + v*100 + k] = a;
  } else if (g < 26200){
    int i = g - 6200;
    int l = i/10000, j = i%10000;
    int h = j/100, k = j%100;
    ws[OFF_WIT + i] = W_ih[(l+1)*10000 + k*100 + h];
  } else if (g < 32600){
    int i = g - 26200;
    int h = i/64, v = i%64;
    ws[OFF_WDT + i] = (v < VV) ? W_dec[v*100 + h] : 0.f;
  } else if (g < 32800){
    int i = g - 32600;
    int l = i/100, k = i%100;
    ws[OFF_BS + i] = b_ih[(l+1)*100 + k] + b_hh[(l+1)*100 + k];
  } else if (g < 32864){
    int i = g - 32800;
    ws[OFF_BDP + i] = (i < VV) ? b_dec[i] : 0.f;
  }
}

// One WG per batch row. Lane k keeps Wh[k][:] in 100 VGPRs; h state in LDS.
__global__ __launch_bounds__(128) void rec_kernel(
    const int* __restrict__ ids, const float* __restrict__ ep,
    const float* __restrict__ Wh, float* __restrict__ buf,
    float* __restrict__ hid, int layer)
{
  __shared__ float4 h4_s[25];
  __shared__ float  ep_s[6200];
  const int b   = blockIdx.x;
  const int tid = threadIdx.x;
  const bool act = tid < HH;
  const int kc = act ? tid : 0;   // clamped lane->k

  float4 wreg[25];
  {
    const float4* w4 = (const float4*)(Wh + kc*HH);
    #pragma unroll
    for (int c=0;c<25;c++) wreg[c] = w4[c];
  }
  if (layer==0){
    for (int i=tid;i<6200;i+=128) ep_s[i] = ep[i];
  }
  if (tid < 25) h4_s[tid] = make_float4(0.f,0.f,0.f,0.f);
  __syncthreads();

  int idn = 0; float xn = 0.f;
  if (layer==0) idn = ids[b*TT];
  else          xn  = buf[(size_t)b*HH + kc];   // row (t=0,b)
  float hn = 0.f;

  for (int t=0;t<TT;t++){
    float xin;
    if (layer==0){
      xin = ep_s[idn*HH + kc];
      if (t+1 < TT) idn = ids[b*TT + t + 1];
    } else {
      xin = xn;
      if (t+1 < TT) xn = buf[((size_t)(t+1)*BB + b)*HH + kc];  // prefetch
    }
    float s0=0.f,s1=0.f,s2=0.f,s3=0.f;
    #pragma unroll
    for (int c=0;c<25;c++){
      float4 w = wreg[c];
      float4 h = h4_s[c];
      s0 = fmaf(w.x,h.x,s0);
      s1 = fmaf(w.y,h.y,s1);
      s2 = fmaf(w.z,h.z,s2);
      s3 = fmaf(w.w,h.w,s3);
    }
    hn = tanh_fast(xin + ((s0+s1)+(s2+s3)));
    __syncthreads();                      // all lanes done reading h_{t-1}
    if (act) ((float*)h4_s)[tid] = hn;
    __syncthreads();                      // h_t visible
    if (act) buf[((size_t)t*BB + b)*HH + tid] = hn;
  }
  if (act) hid[((size_t)layer*BB + b)*HH + tid] = hn;
}

// In-place rows x Wi^T + bias. 128 rows/WG; thread=row; acc[100] in VGPRs;
// weights are wave-uniform loads (scalarizable). LDS transpose for conflict-free access.
__global__ __launch_bounds__(128) void ffn_gemm(
    float* __restrict__ buf, const float* __restrict__ wt,
    const float* __restrict__ bsum)
{
  __shared__ float rt[100*129];
  const int tid = threadIdx.x;
  const size_t rowbase = (size_t)blockIdx.x * 128;
  float4* bin4 = (float4*)(buf + rowbase*HH);

  #pragma unroll
  for (int j=0;j<25;j++){
    int f = j*128 + tid;
    int r = f/25, c = f%25;
    float4 v = bin4[f];
    rt[(4*c+0)*129 + r] = v.x;
    rt[(4*c+1)*129 + r] = v.y;
    rt[(4*c+2)*129 + r] = v.z;
    rt[(4*c+3)*129 + r] = v.w;
  }
  __syncthreads();

  float4 acc[25];
  const float4* bs4 = (const float4*)bsum;
  #pragma unroll
  for (int j=0;j<25;j++) acc[j] = bs4[j];

  for (int h=0; h<HH; h++){
    float rv = rt[h*129 + tid];
    const float4* w4 = (const float4*)(wt + h*HH);
    #pragma unroll
    for (int j=0;j<25;j++){
      float4 w = w4[j];
      acc[j].x = fmaf(rv,w.x,acc[j].x);
      acc[j].y = fmaf(rv,w.y,acc[j].y);
      acc[j].z = fmaf(rv,w.z,acc[j].z);
      acc[j].w = fmaf(rv,w.w,acc[j].w);
    }
  }
  __syncthreads();   // everyone done reading input rows

  #pragma unroll
  for (int j=0;j<25;j++){
    rt[(4*j+0)*129 + tid] = acc[j].x;
    rt[(4*j+1)*129 + tid] = acc[j].y;
    rt[(4*j+2)*129 + tid] = acc[j].z;
    rt[(4*j+3)*129 + tid] = acc[j].w;
  }
  __syncthreads();

  #pragma unroll
  for (int j=0;j<25;j++){
    int f = j*128 + tid;
    int r = f/25, c = f%25;
    float4 v;
    v.x = rt[(4*c+0)*129 + r];
    v.y = rt[(4*c+1)*129 + r];
    v.z = rt[(4*c+2)*129 + r];
    v.w = rt[(4*c+3)*129 + r];
    bin4[f] = v;
  }
}

// Decoder: WG = (b, 128 consecutive t). Output-coalesced. acc over 64 (padded) vocab.
__global__ __launch_bounds__(128) void dec_kernel(
    const float* __restrict__ buf, const float* __restrict__ wdt,
    const float* __restrict__ bdp, float* __restrict__ out)
{
  __shared__ float rt[100*129];
  const int tid = threadIdx.x;
  const int wg  = blockIdx.x;
  const int bb  = wg >> 3;
  const int t0  = (wg & 7) * 128;
  const float4* b4 = (const float4*)buf;

  #pragma unroll
  for (int j=0;j<25;j++){
    int f = j*128 + tid;
    int i = f/25, c = f%25;
    float4 v = b4[((size_t)(t0+i)*BB + bb)*25 + c];
    rt[(4*c+0)*129 + i] = v.x;
    rt[(4*c+1)*129 + i] = v.y;
    rt[(4*c+2)*129 + i] = v.z;
    rt[(4*c+3)*129 + i] = v.w;
  }
  __syncthreads();

  float4 acc[16];
  const float4* bd4 = (const float4*)bdp;
  #pragma unroll
  for (int j=0;j<16;j++) acc[j] = bd4[j];

  for (int h=0; h<HH; h++){
    float rv = rt[h*129 + tid];
    const float4* w4 = (const float4*)(wdt + h*64);
    #pragma unroll
    for (int j=0;j<16;j++){
      float4 w = w4[j];
      acc[j].x = fmaf(rv,w.x,acc[j].x);
      acc[j].y = fmaf(rv,w.y,acc[j].y);
      acc[j].z = fmaf(rv,w.z,acc[j].z);
      acc[j].w = fmaf(rv,w.w,acc[j].w);
    }
  }

  float2* o2 = (float2*)(out + (size_t)(wg*128 + tid)*VV);
  #pragma unroll
  for (int j=0;j<15;j++){
    o2[2*j]   = make_float2(acc[j].x, acc[j].y);
    o2[2*j+1] = make_float2(acc[j].z, acc[j].w);
  }
  o2[30] = make_float2(acc[15].x, acc[15].y);   // v=60,61
}

extern "C" void kernel_launch(void* const* d_in, const int* in_sizes, int n_in,
                              void* d_out, int out_size, void* d_ws, size_t ws_size,
                              hipStream_t stream)
{
  const int*   ids   = (const int*)d_in[0];
  const float* emb   = (const float*)d_in[1];
  const float* W_ih  = (const float*)d_in[2];
  const float* W_hh  = (const float*)d_in[3];
  const float* b_ih  = (const float*)d_in[4];
  const float* b_hh  = (const float*)d_in[5];
  const float* W_dec = (const float*)d_in[6];
  const float* b_dec = (const float*)d_in[7];
  float* out = (float*)d_out;
  float* ws  = (float*)d_ws;
  float* buf = ws;                 // [T][B][H] fp32, ~210 MB, reused in-place
  float* hid = out + BTV;

  prep_kernel<<<129, 256, 0, stream>>>(emb, W_ih, b_ih, b_hh, W_dec, b_dec, ws);

  rec_kernel<<<BB, 128, 0, stream>>>(ids, ws+OFF_EP, W_hh,         buf, hid, 0);
  ffn_gemm  <<<4096, 128, 0, stream>>>(buf, ws+OFF_WIT,         ws+OFF_BS);
  rec_kernel<<<BB, 128, 0, stream>>>(ids, ws+OFF_EP, W_hh + 10000, buf, hid, 1);
  ffn_gemm  <<<4096, 128, 0, stream>>>(buf, ws+OFF_WIT + 10000, ws+OFF_BS + 100);
  rec_kernel<<<BB, 128, 0, stream>>>(ids, ws+OFF_EP, W_hh + 20000, buf, hid, 2);
  dec_kernel<<<4096, 128, 0, stream>>>(buf, ws+OFF_WDT, ws+OFF_BDP, out);
}